// Round 6
// baseline (117.327 us; speedup 1.0000x reference)
//
#include <hip/hip_runtime.h>
#include <hip/hip_fp16.h>

// HMM forward-backward smoother, B=16, T=8192, C=170.
// T = off*11^T + (alpha-off)*I  =>  (u @ T)[j] = off*sum(u) + (alpha-off)*u[j]
// UNNORMALIZED scaled linear recursions (scale cancels in final softmax):
//   fwd:  v' = off*S + dd*u,  S = sum(u),  u = v*l_t   (rescale by 1/S every 4 steps)
//   bwd:  q' = off*S + dd*w,  S = sum(w),  w = l_{t+1}*q
// Wave-wide sum via DPP (v_add_f32_dpp row_shr/row_bcast + readlane 63).
// Round-5/6 changes (attack memory-queueing stall: 36% VALUBusy, 3.7/6.3 TB/s):
//  * LCH=16, 8192 chunks, block=128 = 2 waves/WG, ONE CHUNK PER WAVE:
//    16 WG/CU x 2 waves = 32 waves/CU (8/SIMD, 2x round-4) -> 2x in-flight
//    memory + 2x issue overlap. __launch_bounds__(128,8) pins VGPR<=64.
//  * Nontemporal output stores (native ext_vector f32x2; HIP float2 is a class
//    type the builtin rejects): write-once data stops evicting logits from
//    L2/L3 (bwd + neighbor-warm re-reads were missing to HBM: 130 vs 89 MB).
// float2 class map: lane l owns classes {2l, 2l+1, 128+l} (2 VMEM ops/row).
// p-hat: (p_{2l},p_{2l+1}) __half2 in LDS (4 KB/wave), tail class in 8 VGPRs
// with macro-unrolled LITERAL indices (spill-proof, rule #20).

#define NCLS 170
#define BB 16
#define TT 8192
#define LCH 16
#define WARM 16
#define NCHUNK (TT / LCH)   // 512

typedef float f32x2 __attribute__((ext_vector_type(2)));

struct Row { float x, y, z; };

// 64-lane sum, result broadcast to all lanes via readlane.
__device__ __forceinline__ float wave_sum_b(float x) {
  x += __int_as_float(__builtin_amdgcn_update_dpp(0, __float_as_int(x), 0x111, 0xF, 0xF, true)); // row_shr:1
  x += __int_as_float(__builtin_amdgcn_update_dpp(0, __float_as_int(x), 0x112, 0xF, 0xF, true)); // row_shr:2
  x += __int_as_float(__builtin_amdgcn_update_dpp(0, __float_as_int(x), 0x114, 0xF, 0xF, true)); // row_shr:4
  x += __int_as_float(__builtin_amdgcn_update_dpp(0, __float_as_int(x), 0x118, 0xF, 0xF, true)); // row_shr:8
  x += __int_as_float(__builtin_amdgcn_update_dpp(0, __float_as_int(x), 0x142, 0xA, 0xF, true)); // row_bcast:15
  x += __int_as_float(__builtin_amdgcn_update_dpp(0, __float_as_int(x), 0x143, 0xC, 0xF, true)); // row_bcast:31
  return __int_as_float(__builtin_amdgcn_readlane(__float_as_int(x), 63));
}

__global__ __launch_bounds__(128, 8) void hmm_fb(const float* __restrict__ logits,
                                                 const float* __restrict__ trans,
                                                 const float* __restrict__ initd,
                                                 float* __restrict__ out) {
  __shared__ __half2 pb01[2 * LCH * 64];   // 8 KB: per-wave 4 KB p-hat region
  const int lane = threadIdx.x & 63;
  const int w = threadIdx.x >> 6;          // wave id within WG (independent chunk)
  __half2* pw = pb01 + w * (LCH * 64);

  // XCD-aware swizzle on WGs; adjacent chunks land in the same WG/XCD.
  const int d = blockIdx.x;                 // 4096 WGs
  const int o = (d & 7) * (BB * NCHUNK / 16) + (d >> 3);
  const int g = o * 2 + w;                  // global chunk id, 0..8191
  const int b = g / NCHUNK;
  const int chunk = g % NCHUNK;
  const int t0 = chunk * LCH;
  const int t1 = t0 + LCH;

  // reference uses log(T + 1e-12); reproduce exactly in linear domain
  const float off = trans[1] + 1e-12f;   // off-diagonal element
  const float dia = trans[0] + 1e-12f;   // diagonal element
  const float dd = dia - off;

  const bool cok = (lane < NCLS - 128);  // 42 tail lanes
  const float* lg = logits + (size_t)b * TT * NCLS;

  auto ldraw = [&](int t) -> Row {
    const float* r = lg + (size_t)t * NCLS;
    f32x2 xy = *(const f32x2*)(r + 2 * lane);     // classes 2l, 2l+1 (8B coalesced)
    Row wv;
    wv.x = xy.x;
    wv.y = xy.y;
    wv.z = cok ? r[128 + lane] : 0.f;             // tail class 128+l
    return wv;
  };
  auto eRow = [&](const Row& wv) -> Row {
    Row e;
    e.x = __expf(wv.x);
    e.y = __expf(wv.y);
    e.z = cok ? __expf(wv.z) : 0.f;
    return e;
  };

  __half2 ph2[LCH / 2];   // tail-class p, two steps per reg; LITERAL indices only

  // ---------------- forward ----------------
  float v0, v1, v2s;      // unnormalized predictive message
  auto fcore = [&](const Row& e, float& u0, float& u1, float& u2) -> float {
    u0 = v0 * e.x; u1 = v1 * e.y; u2 = v2s * e.z;   // e.z==0 on invalid lanes
    float S = wave_sum_b(u0 + u1 + u2);
    float os = off * S;
    v0 = __fmaf_rn(dd, u0, os);
    v1 = __fmaf_rn(dd, u1, os);
    v2s = __fmaf_rn(dd, u2, os);
    return S;
  };

  Row a0, a1, a2, a3, b0, b1, b2, b3;
  int ts;
  if (t0 == 0) {
    ts = 0;                                   // exact initial distribution
    f32x2 i01 = *(const f32x2*)(initd + 2 * lane);
    v0 = i01.x; v1 = i01.y; v2s = cok ? initd[128 + lane] : 0.f;
  } else {
    ts = t0 - WARM;                           // warm from uniform
    v0 = 1.f; v1 = 1.f; v2s = cok ? 1.f : 0.f;
  }
  a0 = ldraw(ts); a1 = ldraw(ts + 1); a2 = ldraw(ts + 2); a3 = ldraw(ts + 3);
  b0 = ldraw(ts + 4); b1 = ldraw(ts + 5); b2 = ldraw(ts + 6); b3 = ldraw(ts + 7);

  // warm loop: (t0-ts)/4 = 4 groups interior, 0 for chunk 0; no ph writes
  for (int gg = 0; gg < (t0 - ts) / 4; ++gg) {
    const int tn = ts + 8 + 4 * gg;           // prefetch 2 groups ahead
    Row n0 = ldraw(tn), n1 = ldraw(tn + 1), n2 = ldraw(tn + 2), n3 = ldraw(tn + 3);
    Row e0 = eRow(a0), e1 = eRow(a1), e2 = eRow(a2), e3 = eRow(a3);
    float u0, u1, u2;
    fcore(e0, u0, u1, u2);
    fcore(e1, u0, u1, u2);
    fcore(e2, u0, u1, u2);
    float S3 = fcore(e3, u0, u1, u2);
    float rs = __builtin_amdgcn_rcpf(S3);     // periodic rescale (pure scale)
    v0 *= rs; v1 *= rs; v2s *= rs;
    a0 = b0; a1 = b1; a2 = b2; a3 = b3;
    b0 = n0; b1 = n1; b2 = n2; b3 = n3;
  }
  // handoff: a = rows t0..t0+3, b = rows t0+4..t0+7

// fwd main: macro-unrolled groups of 4; (i) is a literal constant
#define FGROUP(i)                                                              \
  {                                                                            \
    const int tn = t0 + (i) + 8;                                               \
    Row n0 = ldraw(tn + 0 > t1 - 1 ? t1 - 1 : tn + 0);                         \
    Row n1 = ldraw(tn + 1 > t1 - 1 ? t1 - 1 : tn + 1);                         \
    Row n2 = ldraw(tn + 2 > t1 - 1 ? t1 - 1 : tn + 2);                         \
    Row n3 = ldraw(tn + 3 > t1 - 1 ? t1 - 1 : tn + 3);                         \
    Row e0 = eRow(a0), e1 = eRow(a1), e2 = eRow(a2), e3 = eRow(a3);            \
    float u0, u1, u2;                                                          \
    float S0 = fcore(e0, u0, u1, u2);                                          \
    float x0 = __builtin_amdgcn_rcpf(S0);                                      \
    pw[((i) + 0) * 64 + lane] = __floats2half2_rn(u0 * x0, u1 * x0);           \
    __half pa = __float2half(u2 * x0);                                         \
    float S1 = fcore(e1, u0, u1, u2);                                          \
    float x1 = __builtin_amdgcn_rcpf(S1);                                      \
    pw[((i) + 1) * 64 + lane] = __floats2half2_rn(u0 * x1, u1 * x1);           \
    ph2[(i) / 2] = __halves2half2(pa, __float2half(u2 * x1));                  \
    float S2 = fcore(e2, u0, u1, u2);                                          \
    float x2 = __builtin_amdgcn_rcpf(S2);                                      \
    pw[((i) + 2) * 64 + lane] = __floats2half2_rn(u0 * x2, u1 * x2);           \
    __half pb = __float2half(u2 * x2);                                         \
    float S3 = fcore(e3, u0, u1, u2);                                          \
    float x3 = __builtin_amdgcn_rcpf(S3);                                      \
    pw[((i) + 3) * 64 + lane] = __floats2half2_rn(u0 * x3, u1 * x3);           \
    ph2[(i) / 2 + 1] = __halves2half2(pb, __float2half(u2 * x3));              \
    v0 *= x3; v1 *= x3; v2s *= x3;  /* periodic rescale (pure scale) */        \
    a0 = b0; a1 = b1; a2 = b2; a3 = b3;                                        \
    b0 = n0; b1 = n1; b2 = n2; b3 = n3;                                        \
  }

  FGROUP(0) FGROUP(4) FGROUP(8) FGROUP(12)
#undef FGROUP

  // ---------------- backward + fused posterior ----------------
  float q0 = 1.f, q1 = 1.f, q2 = cok ? 1.f : 0.f;   // exact for last chunk (beta_T=0)
  int te2 = t1 + WARM;
  if (te2 > TT) te2 = TT;
  const int tstart = te2 - 1;

  auto ldB = [&](int tp1) -> Row {
    // step at time t uses logits[t+1]; t+1==TT => virtual row logit=0 (l=1)
    int rr = tp1 < 0 ? 0 : (tp1 > TT - 1 ? TT - 1 : tp1);
    Row wv = ldraw(rr);
    if (tp1 >= TT) { wv.x = 0.f; wv.y = 0.f; wv.z = 0.f; }
    return wv;
  };
  auto bcore = [&](const Row& e) -> float {
    float w0 = e.x * q0, w1 = e.y * q1, w2 = e.z * q2;
    float S = wave_sum_b(w0 + w1 + w2);
    float os = off * S;
    q0 = __fmaf_rn(dd, w0, os);
    q1 = __fmaf_rn(dd, w1, os);
    q2 = __fmaf_rn(dd, w2, os);
    return S;
  };

  // banks: a = rows for steps tstart..tstart-3, b = next 4 steps
  a0 = ldB(tstart + 1); a1 = ldB(tstart); a2 = ldB(tstart - 1); a3 = ldB(tstart - 2);
  b0 = ldB(tstart - 3); b1 = ldB(tstart - 4); b2 = ldB(tstart - 5); b3 = ldB(tstart - 6);

  // warm-down: (te2-t1)/4 = 4 groups interior, 0 for last chunk; no ph access
  for (int gg = 0; gg < (te2 - t1) / 4; ++gg) {
    const int tp = tstart - 7 - 4 * gg;       // prefetch rows for 2 groups ahead
    Row n0 = ldB(tp), n1 = ldB(tp - 1), n2 = ldB(tp - 2), n3 = ldB(tp - 3);
    Row e0 = eRow(a0), e1 = eRow(a1), e2 = eRow(a2), e3 = eRow(a3);
    bcore(e0); bcore(e1); bcore(e2);
    float S3 = bcore(e3);
    float rs = __builtin_amdgcn_rcpf(S3);
    q0 *= rs; q1 *= rs; q2 *= rs;
    a0 = b0; a1 = b1; a2 = b2; a3 = b3;
    b0 = n0; b1 = n1; b2 = n2; b3 = n3;
  }
  // handoff: a = rows for steps t1-1..t1-4 (rows t1..t1-3), b = rows t1-4..t1-7

// posterior_t = normalize(p-hat .* q); (tt) is a literal constant
// nontemporal stores: write-once output must not evict logits from L2/L3
#define WPOST(tt, ta)                                                          \
  {                                                                            \
    __half2 h01 = pw[(tt) * 64 + lane];                                        \
    float g0 = __low2float(h01) * q0;                                          \
    float g1 = __high2float(h01) * q1;                                         \
    __half2 h2v = ph2[(tt) >> 1];                                              \
    float p2f = ((tt) & 1) ? __high2float(h2v) : __low2float(h2v);             \
    float g2 = cok ? p2f * q2 : 0.f;                                           \
    float z = wave_sum_b(g0 + g1 + g2);                                        \
    float iz = __builtin_amdgcn_rcpf(z);                                       \
    float* op = out + ((size_t)b * TT + (ta)) * NCLS;                          \
    f32x2 o01; o01.x = g0 * iz; o01.y = g1 * iz;                               \
    __builtin_nontemporal_store(o01, (f32x2*)(op + 2 * lane));                 \
    if (cok) __builtin_nontemporal_store(g2 * iz, op + 128 + lane);            \
  }

// bwd main: macro-unrolled groups of 4; (i) literal; steps t1-1-(i) .. t1-4-(i)
#define BGROUP(i)                                                              \
  {                                                                            \
    const int tp = t1 - 8 - (i);              /* rows for 2 groups ahead */    \
    Row n0 = ldB(tp + 0 < t0 + 1 ? t0 + 1 : tp + 0);                           \
    Row n1 = ldB(tp - 1 < t0 + 1 ? t0 + 1 : tp - 1);                           \
    Row n2 = ldB(tp - 2 < t0 + 1 ? t0 + 1 : tp - 2);                           \
    Row n3 = ldB(tp - 3 < t0 + 1 ? t0 + 1 : tp - 3);                           \
    Row e0 = eRow(a0), e1 = eRow(a1), e2 = eRow(a2), e3 = eRow(a3);            \
    const int t = t1 - 1 - (i);                                                \
    bcore(e0); WPOST(LCH - 1 - (i), t)                                         \
    bcore(e1); WPOST(LCH - 2 - (i), t - 1)                                     \
    bcore(e2); WPOST(LCH - 3 - (i), t - 2)                                     \
    float S3 = bcore(e3); WPOST(LCH - 4 - (i), t - 3)                          \
    float rs = __builtin_amdgcn_rcpf(S3);                                      \
    q0 *= rs; q1 *= rs; q2 *= rs;                                              \
    a0 = b0; a1 = b1; a2 = b2; a3 = b3;                                        \
    b0 = n0; b1 = n1; b2 = n2; b3 = n3;                                        \
  }

  BGROUP(0) BGROUP(4) BGROUP(8) BGROUP(12)
#undef BGROUP
#undef WPOST
}

extern "C" void kernel_launch(void* const* d_in, const int* in_sizes, int n_in,
                              void* d_out, int out_size, void* d_ws, size_t ws_size,
                              hipStream_t stream) {
  const float* logits = (const float*)d_in[0];
  const float* trans  = (const float*)d_in[1];
  const float* initd  = (const float*)d_in[2];
  float* out = (float*)d_out;
  dim3 grid(BB * NCHUNK / 2);   // 4096 WGs x 2 waves = 8192 chunks
  dim3 block(128);
  hipLaunchKernelGGL(hmm_fb, grid, block, 0, stream, logits, trans, initd, out);
}

// Round 7
// 61.410 us; speedup vs baseline: 1.9106x; 1.9106x over previous
//
#include <hip/hip_runtime.h>
#include <hip/hip_fp16.h>

// HMM forward-backward smoother, B=16, T=8192, C=170.
// T = off*11^T + (alpha-off)*I  =>  (u @ T)[j] = off*sum(u) + (alpha-off)*u[j]
// UNNORMALIZED scaled linear recursions (scale cancels in final softmax):
//   fwd:  v' = off*S + dd*u,  S = sum(u),  u = v*l_t   (rescale by 1/S every 4 steps)
//   bwd:  q' = off*S + dd*w,  S = sum(w),  w = l_{t+1}*q
// Wave-wide sum via DPP (v_add_f32_dpp row_shr/row_bcast + readlane 63).
// Round-7 fix: __launch_bounds__(128,4). Empirically this compiler caps
// VGPR = 512/(arg2 * wavesPerBlock): (128,8) gave a 32-VGPR cap -> massive
// scratch spill (WRITE_SIZE 258 MB vs 87.5 MB output, FETCH +120 MB).
// (128,4) -> 64-VGPR cap: fits the ~55-reg pressure, still allows
// 8 waves/EU = 32 waves/CU from the 8192-chunk grid (16 WG/CU x 2 waves,
// LDS 8 KB/WG x 16 = 128 KB <= 160 KB).
//  * LCH=16, 8192 chunks, block=128 = 2 waves/WG, ONE CHUNK PER WAVE.
//  * Nontemporal output stores (native ext_vector f32x2): write-once data
//    stays out of L2/L3 so logits re-reads (bwd + neighbor warmup) hit cache.
// float2 class map: lane l owns classes {2l, 2l+1, 128+l} (2 VMEM ops/row).
// p-hat: (p_{2l},p_{2l+1}) __half2 in LDS (4 KB/wave), tail class in 8 VGPRs
// with macro-unrolled LITERAL indices (spill-proof, rule #20).

#define NCLS 170
#define BB 16
#define TT 8192
#define LCH 16
#define WARM 16
#define NCHUNK (TT / LCH)   // 512

typedef float f32x2 __attribute__((ext_vector_type(2)));

struct Row { float x, y, z; };

// 64-lane sum, result broadcast to all lanes via readlane.
__device__ __forceinline__ float wave_sum_b(float x) {
  x += __int_as_float(__builtin_amdgcn_update_dpp(0, __float_as_int(x), 0x111, 0xF, 0xF, true)); // row_shr:1
  x += __int_as_float(__builtin_amdgcn_update_dpp(0, __float_as_int(x), 0x112, 0xF, 0xF, true)); // row_shr:2
  x += __int_as_float(__builtin_amdgcn_update_dpp(0, __float_as_int(x), 0x114, 0xF, 0xF, true)); // row_shr:4
  x += __int_as_float(__builtin_amdgcn_update_dpp(0, __float_as_int(x), 0x118, 0xF, 0xF, true)); // row_shr:8
  x += __int_as_float(__builtin_amdgcn_update_dpp(0, __float_as_int(x), 0x142, 0xA, 0xF, true)); // row_bcast:15
  x += __int_as_float(__builtin_amdgcn_update_dpp(0, __float_as_int(x), 0x143, 0xC, 0xF, true)); // row_bcast:31
  return __int_as_float(__builtin_amdgcn_readlane(__float_as_int(x), 63));
}

__global__ __launch_bounds__(128, 4) void hmm_fb(const float* __restrict__ logits,
                                                 const float* __restrict__ trans,
                                                 const float* __restrict__ initd,
                                                 float* __restrict__ out) {
  __shared__ __half2 pb01[2 * LCH * 64];   // 8 KB: per-wave 4 KB p-hat region
  const int lane = threadIdx.x & 63;
  const int w = threadIdx.x >> 6;          // wave id within WG (independent chunk)
  __half2* pw = pb01 + w * (LCH * 64);

  // XCD-aware swizzle on WGs; adjacent chunks land in the same WG/XCD.
  const int d = blockIdx.x;                 // 4096 WGs
  const int o = (d & 7) * (BB * NCHUNK / 16) + (d >> 3);
  const int g = o * 2 + w;                  // global chunk id, 0..8191
  const int b = g / NCHUNK;
  const int chunk = g % NCHUNK;
  const int t0 = chunk * LCH;
  const int t1 = t0 + LCH;

  // reference uses log(T + 1e-12); reproduce exactly in linear domain
  const float off = trans[1] + 1e-12f;   // off-diagonal element
  const float dia = trans[0] + 1e-12f;   // diagonal element
  const float dd = dia - off;

  const bool cok = (lane < NCLS - 128);  // 42 tail lanes
  const float* lg = logits + (size_t)b * TT * NCLS;

  auto ldraw = [&](int t) -> Row {
    const float* r = lg + (size_t)t * NCLS;
    f32x2 xy = *(const f32x2*)(r + 2 * lane);     // classes 2l, 2l+1 (8B coalesced)
    Row wv;
    wv.x = xy.x;
    wv.y = xy.y;
    wv.z = cok ? r[128 + lane] : 0.f;             // tail class 128+l
    return wv;
  };
  auto eRow = [&](const Row& wv) -> Row {
    Row e;
    e.x = __expf(wv.x);
    e.y = __expf(wv.y);
    e.z = cok ? __expf(wv.z) : 0.f;
    return e;
  };

  __half2 ph2[LCH / 2];   // tail-class p, two steps per reg; LITERAL indices only

  // ---------------- forward ----------------
  float v0, v1, v2s;      // unnormalized predictive message
  auto fcore = [&](const Row& e, float& u0, float& u1, float& u2) -> float {
    u0 = v0 * e.x; u1 = v1 * e.y; u2 = v2s * e.z;   // e.z==0 on invalid lanes
    float S = wave_sum_b(u0 + u1 + u2);
    float os = off * S;
    v0 = __fmaf_rn(dd, u0, os);
    v1 = __fmaf_rn(dd, u1, os);
    v2s = __fmaf_rn(dd, u2, os);
    return S;
  };

  Row a0, a1, a2, a3, b0, b1, b2, b3;
  int ts;
  if (t0 == 0) {
    ts = 0;                                   // exact initial distribution
    f32x2 i01 = *(const f32x2*)(initd + 2 * lane);
    v0 = i01.x; v1 = i01.y; v2s = cok ? initd[128 + lane] : 0.f;
  } else {
    ts = t0 - WARM;                           // warm from uniform
    v0 = 1.f; v1 = 1.f; v2s = cok ? 1.f : 0.f;
  }
  a0 = ldraw(ts); a1 = ldraw(ts + 1); a2 = ldraw(ts + 2); a3 = ldraw(ts + 3);
  b0 = ldraw(ts + 4); b1 = ldraw(ts + 5); b2 = ldraw(ts + 6); b3 = ldraw(ts + 7);

  // warm loop: (t0-ts)/4 = 4 groups interior, 0 for chunk 0; no ph writes
  for (int gg = 0; gg < (t0 - ts) / 4; ++gg) {
    const int tn = ts + 8 + 4 * gg;           // prefetch 2 groups ahead
    Row n0 = ldraw(tn), n1 = ldraw(tn + 1), n2 = ldraw(tn + 2), n3 = ldraw(tn + 3);
    Row e0 = eRow(a0), e1 = eRow(a1), e2 = eRow(a2), e3 = eRow(a3);
    float u0, u1, u2;
    fcore(e0, u0, u1, u2);
    fcore(e1, u0, u1, u2);
    fcore(e2, u0, u1, u2);
    float S3 = fcore(e3, u0, u1, u2);
    float rs = __builtin_amdgcn_rcpf(S3);     // periodic rescale (pure scale)
    v0 *= rs; v1 *= rs; v2s *= rs;
    a0 = b0; a1 = b1; a2 = b2; a3 = b3;
    b0 = n0; b1 = n1; b2 = n2; b3 = n3;
  }
  // handoff: a = rows t0..t0+3, b = rows t0+4..t0+7

// fwd main: macro-unrolled groups of 4; (i) is a literal constant
#define FGROUP(i)                                                              \
  {                                                                            \
    const int tn = t0 + (i) + 8;                                               \
    Row n0 = ldraw(tn + 0 > t1 - 1 ? t1 - 1 : tn + 0);                         \
    Row n1 = ldraw(tn + 1 > t1 - 1 ? t1 - 1 : tn + 1);                         \
    Row n2 = ldraw(tn + 2 > t1 - 1 ? t1 - 1 : tn + 2);                         \
    Row n3 = ldraw(tn + 3 > t1 - 1 ? t1 - 1 : tn + 3);                         \
    Row e0 = eRow(a0), e1 = eRow(a1), e2 = eRow(a2), e3 = eRow(a3);            \
    float u0, u1, u2;                                                          \
    float S0 = fcore(e0, u0, u1, u2);                                          \
    float x0 = __builtin_amdgcn_rcpf(S0);                                      \
    pw[((i) + 0) * 64 + lane] = __floats2half2_rn(u0 * x0, u1 * x0);           \
    __half pa = __float2half(u2 * x0);                                         \
    float S1 = fcore(e1, u0, u1, u2);                                          \
    float x1 = __builtin_amdgcn_rcpf(S1);                                      \
    pw[((i) + 1) * 64 + lane] = __floats2half2_rn(u0 * x1, u1 * x1);           \
    ph2[(i) / 2] = __halves2half2(pa, __float2half(u2 * x1));                  \
    float S2 = fcore(e2, u0, u1, u2);                                          \
    float x2 = __builtin_amdgcn_rcpf(S2);                                      \
    pw[((i) + 2) * 64 + lane] = __floats2half2_rn(u0 * x2, u1 * x2);           \
    __half pb = __float2half(u2 * x2);                                         \
    float S3 = fcore(e3, u0, u1, u2);                                          \
    float x3 = __builtin_amdgcn_rcpf(S3);                                      \
    pw[((i) + 3) * 64 + lane] = __floats2half2_rn(u0 * x3, u1 * x3);           \
    ph2[(i) / 2 + 1] = __halves2half2(pb, __float2half(u2 * x3));              \
    v0 *= x3; v1 *= x3; v2s *= x3;  /* periodic rescale (pure scale) */        \
    a0 = b0; a1 = b1; a2 = b2; a3 = b3;                                        \
    b0 = n0; b1 = n1; b2 = n2; b3 = n3;                                        \
  }

  FGROUP(0) FGROUP(4) FGROUP(8) FGROUP(12)
#undef FGROUP

  // ---------------- backward + fused posterior ----------------
  float q0 = 1.f, q1 = 1.f, q2 = cok ? 1.f : 0.f;   // exact for last chunk (beta_T=0)
  int te2 = t1 + WARM;
  if (te2 > TT) te2 = TT;
  const int tstart = te2 - 1;

  auto ldB = [&](int tp1) -> Row {
    // step at time t uses logits[t+1]; t+1==TT => virtual row logit=0 (l=1)
    int rr = tp1 < 0 ? 0 : (tp1 > TT - 1 ? TT - 1 : tp1);
    Row wv = ldraw(rr);
    if (tp1 >= TT) { wv.x = 0.f; wv.y = 0.f; wv.z = 0.f; }
    return wv;
  };
  auto bcore = [&](const Row& e) -> float {
    float w0 = e.x * q0, w1 = e.y * q1, w2 = e.z * q2;
    float S = wave_sum_b(w0 + w1 + w2);
    float os = off * S;
    q0 = __fmaf_rn(dd, w0, os);
    q1 = __fmaf_rn(dd, w1, os);
    q2 = __fmaf_rn(dd, w2, os);
    return S;
  };

  // banks: a = rows for steps tstart..tstart-3, b = next 4 steps
  a0 = ldB(tstart + 1); a1 = ldB(tstart); a2 = ldB(tstart - 1); a3 = ldB(tstart - 2);
  b0 = ldB(tstart - 3); b1 = ldB(tstart - 4); b2 = ldB(tstart - 5); b3 = ldB(tstart - 6);

  // warm-down: (te2-t1)/4 = 4 groups interior, 0 for last chunk; no ph access
  for (int gg = 0; gg < (te2 - t1) / 4; ++gg) {
    const int tp = tstart - 7 - 4 * gg;       // prefetch rows for 2 groups ahead
    Row n0 = ldB(tp), n1 = ldB(tp - 1), n2 = ldB(tp - 2), n3 = ldB(tp - 3);
    Row e0 = eRow(a0), e1 = eRow(a1), e2 = eRow(a2), e3 = eRow(a3);
    bcore(e0); bcore(e1); bcore(e2);
    float S3 = bcore(e3);
    float rs = __builtin_amdgcn_rcpf(S3);
    q0 *= rs; q1 *= rs; q2 *= rs;
    a0 = b0; a1 = b1; a2 = b2; a3 = b3;
    b0 = n0; b1 = n1; b2 = n2; b3 = n3;
  }
  // handoff: a = rows for steps t1-1..t1-4 (rows t1..t1-3), b = rows t1-4..t1-7

// posterior_t = normalize(p-hat .* q); (tt) is a literal constant
// nontemporal stores: write-once output must not evict logits from L2/L3
#define WPOST(tt, ta)                                                          \
  {                                                                            \
    __half2 h01 = pw[(tt) * 64 + lane];                                        \
    float g0 = __low2float(h01) * q0;                                          \
    float g1 = __high2float(h01) * q1;                                         \
    __half2 h2v = ph2[(tt) >> 1];                                              \
    float p2f = ((tt) & 1) ? __high2float(h2v) : __low2float(h2v);             \
    float g2 = cok ? p2f * q2 : 0.f;                                           \
    float z = wave_sum_b(g0 + g1 + g2);                                        \
    float iz = __builtin_amdgcn_rcpf(z);                                       \
    float* op = out + ((size_t)b * TT + (ta)) * NCLS;                          \
    f32x2 o01; o01.x = g0 * iz; o01.y = g1 * iz;                               \
    __builtin_nontemporal_store(o01, (f32x2*)(op + 2 * lane));                 \
    if (cok) __builtin_nontemporal_store(g2 * iz, op + 128 + lane);            \
  }

// bwd main: macro-unrolled groups of 4; (i) literal; steps t1-1-(i) .. t1-4-(i)
#define BGROUP(i)                                                              \
  {                                                                            \
    const int tp = t1 - 8 - (i);              /* rows for 2 groups ahead */    \
    Row n0 = ldB(tp + 0 < t0 + 1 ? t0 + 1 : tp + 0);                           \
    Row n1 = ldB(tp - 1 < t0 + 1 ? t0 + 1 : tp - 1);                           \
    Row n2 = ldB(tp - 2 < t0 + 1 ? t0 + 1 : tp - 2);                           \
    Row n3 = ldB(tp - 3 < t0 + 1 ? t0 + 1 : tp - 3);                           \
    Row e0 = eRow(a0), e1 = eRow(a1), e2 = eRow(a2), e3 = eRow(a3);            \
    const int t = t1 - 1 - (i);                                                \
    bcore(e0); WPOST(LCH - 1 - (i), t)                                         \
    bcore(e1); WPOST(LCH - 2 - (i), t - 1)                                     \
    bcore(e2); WPOST(LCH - 3 - (i), t - 2)                                     \
    float S3 = bcore(e3); WPOST(LCH - 4 - (i), t - 3)                          \
    float rs = __builtin_amdgcn_rcpf(S3);                                      \
    q0 *= rs; q1 *= rs; q2 *= rs;                                              \
    a0 = b0; a1 = b1; a2 = b2; a3 = b3;                                        \
    b0 = n0; b1 = n1; b2 = n2; b3 = n3;                                        \
  }

  BGROUP(0) BGROUP(4) BGROUP(8) BGROUP(12)
#undef BGROUP
#undef WPOST
}

extern "C" void kernel_launch(void* const* d_in, const int* in_sizes, int n_in,
                              void* d_out, int out_size, void* d_ws, size_t ws_size,
                              hipStream_t stream) {
  const float* logits = (const float*)d_in[0];
  const float* trans  = (const float*)d_in[1];
  const float* initd  = (const float*)d_in[2];
  float* out = (float*)d_out;
  dim3 grid(BB * NCHUNK / 2);   // 4096 WGs x 2 waves = 8192 chunks
  dim3 block(128);
  hipLaunchKernelGGL(hmm_fb, grid, block, 0, stream, logits, trans, initd, out);
}